// Round 11
// baseline (137.471 us; speedup 1.0000x reference)
//
#include <hip/hip_runtime.h>

typedef short v4s __attribute__((ext_vector_type(4)));
typedef float v4f __attribute__((ext_vector_type(4)));
typedef unsigned int v2u __attribute__((ext_vector_type(2)));
union FU { v2u u; v4s s; };

static __device__ __forceinline__ float bf16_to_f32(unsigned short u){
    return __uint_as_float(((unsigned int)u)<<16);
}

// f32 -> e4m3 byte, RNE, positive normal range only (our values are in [0.45, 2]).
static __device__ __forceinline__ unsigned int f32_to_e4m3(float x){
    unsigned int u = __float_as_uint(x);
    unsigned int mr = (u & 0x7FFFFFu) + 0x7FFFFu + ((u>>20)&1u);  // RNE to 3 mantissa bits
    unsigned int e  = ((u>>23)&255u) + (mr>>23);                   // carry bump
    return ((e-120u)<<3) | ((mr>>20)&7u);                          // (e-127+7)<<3 | m3
}
// e4m3 byte -> f32 (normal, positive)
static __device__ __forceinline__ float e4m3_to_f32(unsigned int b){
    return __uint_as_float(((b<<4) + 0x3C00u)<<16);
}
// 4 e4m3 bytes (one dword) -> bf16x4 as two dwords {elem0|elem1<<16, elem2|elem3<<16}
// bf16 = (byte<<4) + 0x3C00 exactly (e4m3 normals are exact in bf16).
// Per-16-bit-half sums < 0x10000, so one packed add works.
static __device__ __forceinline__ v2u dec8(unsigned int d){
    unsigned int lo = (((d & 0xFFu)<<4) | ((d & 0xFF00u)<<12)) + 0x3C003C00u;
    unsigned int t  = d >> 16;
    unsigned int hi = (((t & 0xFFu)<<4) | ((t & 0xFF00u)<<12)) + 0x3C003C00u;
    return (v2u){lo, hi};
}

// Packed f32x4 -> bf16x4 via v_cvt_pk_bf16_f32 with MFMA-hazard s_nop guards
// (validated rounds 2-9).
#define CVT_ACC_TO_B(lo, hi, acc) \
    asm("s_nop 1\n\t" \
        "v_cvt_pk_bf16_f32 %0, %2, %3\n\t" \
        "v_cvt_pk_bf16_f32 %1, %4, %5\n\t" \
        "s_nop 1" \
        : "=&v"(lo), "=&v"(hi) \
        : "v"(acc[0]), "v"(acc[1]), "v"(acc[2]), "v"(acc[3]))

#define SPW 4   // samples per wave

// ws layout (fp8):
// [0,1MB)        cores8  e4m3 [16][256][16][16] row-major = softplus(lc)*4096
// [1MB,2MB)      coresT8 e4m3, inner 16x16 transposed (M^T row-major)
// [2MB,+64KB)    bars4 f32[4][16*256] partial column sums (row-major table)
// [2MB+64KB,+4)  lognorm_total = log_norm_ref + 192*ln2

__global__ void k_softplus_fp8(const float* __restrict__ lc,
                               unsigned int* __restrict__ c8,
                               unsigned int* __restrict__ cT8){
    int t = blockIdx.x*256 + threadIdx.x;        // 262144 threads, 4 elems each table
    // normal table: 4 consecutive row-major elements
    float4 v = ((const float4*)lc)[t];
    float s0 = (v.x>20.f)?v.x:log1pf(expf(v.x));
    float s1 = (v.y>20.f)?v.y:log1pf(expf(v.y));
    float s2 = (v.z>20.f)?v.z:log1pf(expf(v.z));
    float s3 = (v.w>20.f)?v.w:log1pf(expf(v.w));
    unsigned int d = f32_to_e4m3(s0*4096.f) | (f32_to_e4m3(s1*4096.f)<<8)
                   | (f32_to_e4m3(s2*4096.f)<<16) | (f32_to_e4m3(s3*4096.f)<<24);
    c8[t] = d;
    // transposed table: element f=t*4 -> [md][c][r..r+3] = M[r..r+3][c]
    // (same mapping as validated r2 k_softplus2 / r10 k_softplus3 transpose)
    int f  = t<<2;
    int md = f>>8, c = (f>>4)&15, r = f&15;
    const float* s = lc + (md<<8) + c;
    float x0 = s[(r+0)<<4], x1 = s[(r+1)<<4], x2 = s[(r+2)<<4], x3 = s[(r+3)<<4];
    x0 = (x0>20.f)?x0:log1pf(expf(x0));
    x1 = (x1>20.f)?x1:log1pf(expf(x1));
    x2 = (x2>20.f)?x2:log1pf(expf(x2));
    x3 = (x3>20.f)?x3:log1pf(expf(x3));
    unsigned int dT = f32_to_e4m3(x0*4096.f) | (f32_to_e4m3(x1*4096.f)<<8)
                    | (f32_to_e4m3(x2*4096.f)<<16) | (f32_to_e4m3(x3*4096.f)<<24);
    cT8[t] = dT;
}

// 64 blocks: block b sums d-range [64*(b&3),+64) of mode b>>2 over the fp8
// row-major table (deterministic partials, no atomics).
__global__ void k_bars_fp8(const unsigned char* __restrict__ c8, float* __restrict__ bars4){
    int b = blockIdx.x, t = threadIdx.x;
    int m = b>>2, dq = b&3;
    const unsigned char* p = c8 + m*65536 + dq*64*256 + t;
    float s = 0.f;
    #pragma unroll 16
    for (int d=0; d<64; d++) s += e4m3_to_f32(p[d*256]);
    bars4[dq*4096 + m*256 + t] = s;
}

// validated r7 version (row-major bars)
__global__ void k_norm2(const float* __restrict__ bars4, float* __restrict__ lognorm){
    __shared__ float sbars[16*256];
    __shared__ float cur[256];
    int t = threadIdx.x, i = t>>4, j = t&15;
    for (int m=0;m<16;m++){
        int o = m*256 + t;
        sbars[o] = bars4[o] + bars4[4096+o] + bars4[8192+o] + bars4[12288+o];
    }
    cur[t] = (i==j)?1.f:0.f;
    __syncthreads();
    for (int m=0;m<16;m++){
        float s = 0.f;
        #pragma unroll
        for (int k=0;k<16;k++) s += cur[i*16+k]*sbars[m*256 + k*16 + j];
        s *= 0.000244140625f; // 2^-12 cancels the 4096x core scale
        __syncthreads();
        cur[t] = s;
        __syncthreads();
    }
    if (t==0){
        float tr=0.f;
        #pragma unroll
        for (int k=0;k<16;k++) tr += cur[k*17];
        lognorm[0] = logf(tr) + 192.0f*0.69314718055994531f; // + log(4096^16)
    }
}

// fp8 gathers with wave-uniform (SGPR) indices: 4 B/lane, half of round 7-9.
static __device__ __forceinline__ void gather8(unsigned int* F8, const int* __restrict__ ip,
        const unsigned char* __restrict__ c8, const unsigned char* __restrict__ cT8,
        int laneoffB){
    #pragma unroll
    for (int k=0;k<16;k++){
        int ix = ip[k];                                // scalar load
        const unsigned char* tp = (k&1)? cT8 : c8;
        F8[k] = *(const unsigned int*)(tp + (((k<<8)|ix)<<8) + laneoffB);
    }
}

// Binary-tree trace halves (math validated rounds 4-9); level 1 decodes fp8.
// A-frag(X) == B-frag(X^T); MFMA D-frag == B-frag(D).
static __device__ __forceinline__ void tree_level1_fp8(const unsigned int* F8,
        unsigned int* c1lo, unsigned int* c1hi){
    #pragma unroll
    for (int i=0;i<8;i++){
        v2u fe = dec8(F8[2*i]);      // even leaf: cores (A-layout of M)
        v2u fo = dec8(F8[2*i+1]);    // odd leaf: coresT (B-layout of M)
        FU A,B;
        if (i&1){ A.u=fe; B.u=fo; }  // right-oriented (same roles as r7's F[2i],F[2i+1])
        else    { A.u=fo; B.u=fe; }  // left-oriented (P^T)
        v4f z={0.f,0.f,0.f,0.f};
        v4f acc=__builtin_amdgcn_mfma_f32_16x16x16bf16_1k(A.s,B.s,z,0,0,0);
        CVT_ACC_TO_B(c1lo[i],c1hi[i],acc);
    }
}
static __device__ __forceinline__ float tree_level23(const unsigned int* c1lo,
        const unsigned int* c1hi){
    unsigned int c2lo[4], c2hi[4];
    #pragma unroll
    for (int j=0;j<4;j++){
        FU A,B;
        if (j&1){ A.u=(v2u){c1lo[2*j],c1hi[2*j]};     B.u=(v2u){c1lo[2*j+1],c1hi[2*j+1]}; }
        else    { A.u=(v2u){c1lo[2*j+1],c1hi[2*j+1]}; B.u=(v2u){c1lo[2*j],c1hi[2*j]};     }
        v4f z={0.f,0.f,0.f,0.f};
        v4f acc=__builtin_amdgcn_mfma_f32_16x16x16bf16_1k(A.s,B.s,z,0,0,0);
        CVT_ACC_TO_B(c2lo[j],c2hi[j],acc);
    }
    FU A0,B0,A1,B1;
    A0.u=(v2u){c2lo[1],c2hi[1]}; B0.u=(v2u){c2lo[0],c2hi[0]};
    A1.u=(v2u){c2lo[2],c2hi[2]}; B1.u=(v2u){c2lo[3],c2hi[3]};
    v4f z={0.f,0.f,0.f,0.f};
    v4f aL=__builtin_amdgcn_mfma_f32_16x16x16bf16_1k(A0.s,B0.s,z,0,0,0);
    v4f aR=__builtin_amdgcn_mfma_f32_16x16x16bf16_1k(A1.s,B1.s,z,0,0,0);
    return aL[0]*aR[0]+aL[1]*aR[1]+aL[2]*aR[2]+aL[3]*aR[3];
}

__global__ __launch_bounds__(256) void k_chain10(const int* __restrict__ idx,
    const unsigned char* __restrict__ c8, const unsigned char* __restrict__ cT8,
    const float* __restrict__ lognorm, float* __restrict__ out)
{
    const int lane = threadIdx.x & 63;
    const int wq   = __builtin_amdgcn_readfirstlane(threadIdx.x >> 6);
    const int wave = (blockIdx.x<<2) + wq;
    const int col  = lane & 15;
    const int laneoffB = col*16 + (((lane>>4)&3)<<2);   // BYTES (1 B/elem), dword-aligned
    const float L = lognorm[0];
    const int s0 = wave * SPW;
    const int* __restrict__ ip = idx + (s0<<4);

    unsigned int FA[16], FB[16];
    unsigned int c1lo[8], c1hi[8];
    float d0,d1,d2,d3;

    gather8(FA, ip,    c8, cT8, laneoffB);
    tree_level1_fp8(FA, c1lo, c1hi);
    gather8(FB, ip+16, c8, cT8, laneoffB);
    d0 = tree_level23(c1lo, c1hi);

    tree_level1_fp8(FB, c1lo, c1hi);
    gather8(FA, ip+32, c8, cT8, laneoffB);
    d1 = tree_level23(c1lo, c1hi);

    tree_level1_fp8(FA, c1lo, c1hi);
    gather8(FB, ip+48, c8, cT8, laneoffB);
    d2 = tree_level23(c1lo, c1hi);

    tree_level1_fp8(FB, c1lo, c1hi);
    d3 = tree_level23(c1lo, c1hi);

    // batched butterfly: 4 independent chains (validated rounds 8-9)
    #pragma unroll
    for (int off=32; off>0; off>>=1){
        d0 += __shfl_xor(d0, off, 64);
        d1 += __shfl_xor(d1, off, 64);
        d2 += __shfl_xor(d2, off, 64);
        d3 += __shfl_xor(d3, off, 64);
    }
    float res = (lane==0)?d0:(lane==1)?d1:(lane==2)?d2:(lane==3)?d3:0.f;

    if (lane < SPW){
        float o;
        if (!(L > -1e30f && L < 1e30f)) o = -5555.0f;   // lognorm bad
        else if (res > 0.f)             o = logf(res) - L;
        else                            o = -6666.0f;   // non-positive trace
        out[s0 + lane] = o;
    }
}

extern "C" void kernel_launch(void* const* d_in, const int* in_sizes, int n_in,
                              void* d_out, int out_size, void* d_ws, size_t ws_size,
                              hipStream_t stream)
{
    const int*   idx = (const int*)d_in[0];
    const float* lc  = (const float*)d_in[1];
    float* out = (float*)d_out;

    const size_t C8_B    = (size_t)16*256*256;            // 1MB per fp8 table
    const size_t BARS4_B = (size_t)4*16*256*4;            // 64KB
    const size_t WS_NEED = 2*C8_B + BARS4_B + 4;
    if (ws_size < WS_NEED) return;   // signature: out stays 0 -> absmax ~= 89

    unsigned int* c8   = (unsigned int*)d_ws;
    unsigned int* cT8  = (unsigned int*)((char*)d_ws + C8_B);
    float* bars4   = (float*)((char*)d_ws + 2*C8_B);
    float* lognorm = (float*)((char*)d_ws + 2*C8_B + BARS4_B);

    k_softplus_fp8<<<1024, 256, 0, stream>>>(lc, c8, cT8);
    k_bars_fp8    <<<64,   256, 0, stream>>>((const unsigned char*)c8, bars4);
    k_norm2       <<<1,    256, 0, stream>>>(bars4, lognorm);
    int nblocks = out_size / (SPW*4);   // 4 waves/block -> 8192 blocks
    k_chain10     <<<nblocks, 256, 0, stream>>>(idx, (const unsigned char*)c8,
                                                (const unsigned char*)cT8, lognorm, out);
}

// Round 12
// 82.566 us; speedup vs baseline: 1.6650x; 1.6650x over previous
//
#include <hip/hip_runtime.h>

typedef short v4s __attribute__((ext_vector_type(4)));
typedef float v4f __attribute__((ext_vector_type(4)));
typedef unsigned int v2u __attribute__((ext_vector_type(2)));
union FU { v2u u; v4s s; };
union FL { v2u u; long long l; };

// f32 -> e4m3 byte, RNE, positive normal range only (values in [0.45, 2]).
// Validated round 11 (absmax 0.5).
static __device__ __forceinline__ unsigned int f32_to_e4m3(float x){
    unsigned int u = __float_as_uint(x);
    unsigned int mr = (u & 0x7FFFFFu) + 0x7FFFFu + ((u>>20)&1u);  // RNE to 3 mantissa bits
    unsigned int e  = ((u>>23)&255u) + (mr>>23);                   // carry bump
    return ((e-120u)<<3) | ((mr>>20)&7u);                          // (e-127+7)<<3 | m3
}
static __device__ __forceinline__ float e4m3_to_f32(unsigned int b){
    return __uint_as_float(((b<<4) + 0x3C00u)<<16);
}

// Packed f32x4 -> bf16x4 via v_cvt_pk_bf16_f32 with MFMA-hazard s_nop guards
// (validated rounds 2-11).
#define CVT_ACC_TO_B(lo, hi, acc) \
    asm("s_nop 1\n\t" \
        "v_cvt_pk_bf16_f32 %0, %2, %3\n\t" \
        "v_cvt_pk_bf16_f32 %1, %4, %5\n\t" \
        "s_nop 1" \
        : "=&v"(lo), "=&v"(hi) \
        : "v"(acc[0]), "v"(acc[1]), "v"(acc[2]), "v"(acc[3]))

#define SPW 4   // samples per wave

// ws layout (fp8, same as validated round 11):
// [0,1MB)        cores8  e4m3 [16][256][16][16] row-major = softplus(lc)*4096
// [1MB,2MB)      coresT8 e4m3, inner 16x16 transposed (M^T row-major)
// [2MB,+64KB)    bars4 f32[4][16*256] partial column sums (row-major table)
// [2MB+64KB,+4)  lognorm_total = log_norm_ref + 192*ln2

__global__ void k_softplus_fp8(const float* __restrict__ lc,
                               unsigned int* __restrict__ c8,
                               unsigned int* __restrict__ cT8){
    int t = blockIdx.x*256 + threadIdx.x;
    float4 v = ((const float4*)lc)[t];
    float s0 = (v.x>20.f)?v.x:log1pf(expf(v.x));
    float s1 = (v.y>20.f)?v.y:log1pf(expf(v.y));
    float s2 = (v.z>20.f)?v.z:log1pf(expf(v.z));
    float s3 = (v.w>20.f)?v.w:log1pf(expf(v.w));
    unsigned int d = f32_to_e4m3(s0*4096.f) | (f32_to_e4m3(s1*4096.f)<<8)
                   | (f32_to_e4m3(s2*4096.f)<<16) | (f32_to_e4m3(s3*4096.f)<<24);
    c8[t] = d;
    int f  = t<<2;
    int md = f>>8, c = (f>>4)&15, r = f&15;
    const float* s = lc + (md<<8) + c;
    float x0 = s[(r+0)<<4], x1 = s[(r+1)<<4], x2 = s[(r+2)<<4], x3 = s[(r+3)<<4];
    x0 = (x0>20.f)?x0:log1pf(expf(x0));
    x1 = (x1>20.f)?x1:log1pf(expf(x1));
    x2 = (x2>20.f)?x2:log1pf(expf(x2));
    x3 = (x3>20.f)?x3:log1pf(expf(x3));
    unsigned int dT = f32_to_e4m3(x0*4096.f) | (f32_to_e4m3(x1*4096.f)<<8)
                    | (f32_to_e4m3(x2*4096.f)<<16) | (f32_to_e4m3(x3*4096.f)<<24);
    cT8[t] = dT;
}

__global__ void k_bars_fp8(const unsigned char* __restrict__ c8, float* __restrict__ bars4){
    int b = blockIdx.x, t = threadIdx.x;
    int m = b>>2, dq = b&3;
    const unsigned char* p = c8 + m*65536 + dq*64*256 + t;
    float s = 0.f;
    #pragma unroll 16
    for (int d=0; d<64; d++) s += e4m3_to_f32(p[d*256]);
    bars4[dq*4096 + m*256 + t] = s;
}

__global__ void k_norm2(const float* __restrict__ bars4, float* __restrict__ lognorm){
    __shared__ float sbars[16*256];
    __shared__ float cur[256];
    int t = threadIdx.x, i = t>>4, j = t&15;
    for (int m=0;m<16;m++){
        int o = m*256 + t;
        sbars[o] = bars4[o] + bars4[4096+o] + bars4[8192+o] + bars4[12288+o];
    }
    cur[t] = (i==j)?1.f:0.f;
    __syncthreads();
    for (int m=0;m<16;m++){
        float s = 0.f;
        #pragma unroll
        for (int k=0;k<16;k++) s += cur[i*16+k]*sbars[m*256 + k*16 + j];
        s *= 0.000244140625f; // 2^-12 cancels the 4096x core scale
        __syncthreads();
        cur[t] = s;
        __syncthreads();
    }
    if (t==0){
        float tr=0.f;
        #pragma unroll
        for (int k=0;k<16;k++) tr += cur[k*17];
        lognorm[0] = logf(tr) + 192.0f*0.69314718055994531f; // + log(4096^16)
    }
}

// fp8 leaf gathers: every lane reads 8 CONSECUTIVE bytes of row (lane&15) at
// k-offset ((lane>>4)&1)*8; lanes 32-63 mirror 0-31 (same cache lines).
// 256B unique per matrix = 4 lines (bf16 was 8).
static __device__ __forceinline__ void gather8b(v2u* F, const int* __restrict__ ip,
        const unsigned char* __restrict__ c8, const unsigned char* __restrict__ cT8,
        int laneoffB){
    #pragma unroll
    for (int k=0;k<16;k++){
        int ix = ip[k];                                // scalar load (wave-uniform)
        const unsigned char* tp = (k&1)? cT8 : c8;
        F[k] = *(const v2u*)(tp + (((k<<8)|ix)<<8) + laneoffB);
    }
}

// Level 1 via native fp8 MFMA, K padded 16->32: A lanes 32-63 = 0 (k>=16 dead),
// B lanes 32-63 = mirrored bytes (multiplied by zero A, don't-care).
// Role assignment identical to validated r7/r11 orientation logic:
//   right (i&1): A = even leaf (c8 rows: M_even), B = odd leaf (cT8 rows: B-frag(M_odd))
//   left  else : A = odd leaf (cT8 rows: M_odd^T), B = even leaf (c8 rows: B-frag(M_even^T))
static __device__ __forceinline__ void tree_level1_f8m(const v2u* F, bool alive,
        unsigned int* c1lo, unsigned int* c1hi){
    #pragma unroll
    for (int i=0;i<8;i++){
        v2u fe = F[2*i];
        v2u fo = F[2*i+1];
        v2u asel = (i&1)? fe : fo;
        v2u az = alive ? asel : (v2u){0u,0u};
        v2u bz = (i&1)? fo : fe;
        FL A; A.u = az;
        FL B; B.u = bz;
        v4f z = {0.f,0.f,0.f,0.f};
        v4f acc = __builtin_amdgcn_mfma_f32_16x16x32_fp8_fp8(A.l, B.l, z, 0,0,0);
        CVT_ACC_TO_B(c1lo[i], c1hi[i], acc);
    }
}

// Levels 2-3, bf16 (validated rounds 4-11 verbatim).
static __device__ __forceinline__ float tree_level23(const unsigned int* c1lo,
        const unsigned int* c1hi){
    unsigned int c2lo[4], c2hi[4];
    #pragma unroll
    for (int j=0;j<4;j++){
        FU A,B;
        if (j&1){ A.u=(v2u){c1lo[2*j],c1hi[2*j]};     B.u=(v2u){c1lo[2*j+1],c1hi[2*j+1]}; }
        else    { A.u=(v2u){c1lo[2*j+1],c1hi[2*j+1]}; B.u=(v2u){c1lo[2*j],c1hi[2*j]};     }
        v4f z={0.f,0.f,0.f,0.f};
        v4f acc=__builtin_amdgcn_mfma_f32_16x16x16bf16_1k(A.s,B.s,z,0,0,0);
        CVT_ACC_TO_B(c2lo[j],c2hi[j],acc);
    }
    FU A0,B0,A1,B1;
    A0.u=(v2u){c2lo[1],c2hi[1]}; B0.u=(v2u){c2lo[0],c2hi[0]};
    A1.u=(v2u){c2lo[2],c2hi[2]}; B1.u=(v2u){c2lo[3],c2hi[3]};
    v4f z={0.f,0.f,0.f,0.f};
    v4f aL=__builtin_amdgcn_mfma_f32_16x16x16bf16_1k(A0.s,B0.s,z,0,0,0);
    v4f aR=__builtin_amdgcn_mfma_f32_16x16x16bf16_1k(A1.s,B1.s,z,0,0,0);
    return aL[0]*aR[0]+aL[1]*aR[1]+aL[2]*aR[2]+aL[3]*aR[3];
}

__global__ __launch_bounds__(256) void k_chain11(const int* __restrict__ idx,
    const unsigned char* __restrict__ c8, const unsigned char* __restrict__ cT8,
    const float* __restrict__ lognorm, float* __restrict__ out)
{
    const int lane = threadIdx.x & 63;
    const int wq   = __builtin_amdgcn_readfirstlane(threadIdx.x >> 6);
    const int wave = (blockIdx.x<<2) + wq;
    const int row  = lane & 15;
    const int klo  = (lane>>4)&1;
    const int laneoffB = row*16 + klo*8;     // bytes; lanes 32-63 mirror 0-31
    const bool alive = (lane < 32);          // A-operand live lanes (k < 16)
    const float L = lognorm[0];
    const int s0 = wave * SPW;
    const int* __restrict__ ip = idx + (s0<<4);

    v2u FA[16], FB[16];
    unsigned int c1lo[8], c1hi[8];
    float d0,d1,d2,d3;

    gather8b(FA, ip,    c8, cT8, laneoffB);
    tree_level1_f8m(FA, alive, c1lo, c1hi);
    gather8b(FB, ip+16, c8, cT8, laneoffB);
    d0 = tree_level23(c1lo, c1hi);

    tree_level1_f8m(FB, alive, c1lo, c1hi);
    gather8b(FA, ip+32, c8, cT8, laneoffB);
    d1 = tree_level23(c1lo, c1hi);

    tree_level1_f8m(FA, alive, c1lo, c1hi);
    gather8b(FB, ip+48, c8, cT8, laneoffB);
    d2 = tree_level23(c1lo, c1hi);

    tree_level1_f8m(FB, alive, c1lo, c1hi);
    d3 = tree_level23(c1lo, c1hi);

    // batched butterfly: 4 independent chains (validated rounds 8-11)
    #pragma unroll
    for (int off=32; off>0; off>>=1){
        d0 += __shfl_xor(d0, off, 64);
        d1 += __shfl_xor(d1, off, 64);
        d2 += __shfl_xor(d2, off, 64);
        d3 += __shfl_xor(d3, off, 64);
    }
    float res = (lane==0)?d0:(lane==1)?d1:(lane==2)?d2:(lane==3)?d3:0.f;

    if (lane < SPW){
        float o;
        if (!(L > -1e30f && L < 1e30f)) o = -5555.0f;   // lognorm bad
        else if (res > 0.f)             o = logf(res) - L;
        else                            o = -6666.0f;   // non-positive trace
        out[s0 + lane] = o;
    }
}

extern "C" void kernel_launch(void* const* d_in, const int* in_sizes, int n_in,
                              void* d_out, int out_size, void* d_ws, size_t ws_size,
                              hipStream_t stream)
{
    const int*   idx = (const int*)d_in[0];
    const float* lc  = (const float*)d_in[1];
    float* out = (float*)d_out;

    const size_t C8_B    = (size_t)16*256*256;            // 1MB per fp8 table
    const size_t BARS4_B = (size_t)4*16*256*4;            // 64KB
    const size_t WS_NEED = 2*C8_B + BARS4_B + 4;
    if (ws_size < WS_NEED) return;   // signature: out stays 0 -> absmax ~= 89

    unsigned int* c8   = (unsigned int*)d_ws;
    unsigned int* cT8  = (unsigned int*)((char*)d_ws + C8_B);
    float* bars4   = (float*)((char*)d_ws + 2*C8_B);
    float* lognorm = (float*)((char*)d_ws + 2*C8_B + BARS4_B);

    k_softplus_fp8<<<1024, 256, 0, stream>>>(lc, c8, cT8);
    k_bars_fp8    <<<64,   256, 0, stream>>>((const unsigned char*)c8, bars4);
    k_norm2       <<<1,    256, 0, stream>>>(bars4, lognorm);
    int nblocks = out_size / (SPW*4);   // 4 waves/block -> 8192 blocks
    k_chain11     <<<nblocks, 256, 0, stream>>>(idx, (const unsigned char*)c8,
                                                (const unsigned char*)cT8, lognorm, out);
}

// Round 13
// 65.970 us; speedup vs baseline: 2.0838x; 1.2516x over previous
//
#include <hip/hip_runtime.h>

typedef short v4s __attribute__((ext_vector_type(4)));
typedef float v4f __attribute__((ext_vector_type(4)));
typedef unsigned int v2u __attribute__((ext_vector_type(2)));
union FU { v2u u; v4s s; };
union FL { v2u u; long long l; };

// f32 -> e4m3 byte, RNE, positive normal range (values in [0.45, 2]).
// Validated rounds 11-12 (absmax 0.5).
static __device__ __forceinline__ unsigned int f32_to_e4m3(float x){
    unsigned int u = __float_as_uint(x);
    unsigned int mr = (u & 0x7FFFFFu) + 0x7FFFFu + ((u>>20)&1u);  // RNE to 3 mantissa bits
    unsigned int e  = ((u>>23)&255u) + (mr>>23);                   // carry bump
    return ((e-120u)<<3) | ((mr>>20)&7u);                          // (e-127+7)<<3 | m3
}
static __device__ __forceinline__ float e4m3_to_f32(unsigned int b){
    return __uint_as_float(((b<<4) + 0x3C00u)<<16);
}

// Packed f32x4 -> bf16x4 via v_cvt_pk_bf16_f32 with MFMA-hazard s_nop guards
// (validated rounds 2-12).
#define CVT_ACC_TO_B(lo, hi, acc) \
    asm("s_nop 1\n\t" \
        "v_cvt_pk_bf16_f32 %0, %2, %3\n\t" \
        "v_cvt_pk_bf16_f32 %1, %4, %5\n\t" \
        "s_nop 1" \
        : "=&v"(lo), "=&v"(hi) \
        : "v"(acc[0]), "v"(acc[1]), "v"(acc[2]), "v"(acc[3]))

#define SPW 4   // samples per wave = 2 pairs; 8 gathers/sample (was 16)

// ws layout (fp8, validated rounds 11-12):
// [0,1MB)        cores8  e4m3 [16][256][16][16] row-major = softplus(lc)*4096
// [1MB,2MB)      coresT8 e4m3, inner 16x16 transposed (M^T row-major)
// [2MB,+64KB)    bars4 f32[4][16*256] partial column sums (row-major table)
// [2MB+64KB,+4)  lognorm_total = log_norm_ref + 192*ln2

__global__ void k_softplus_fp8(const float* __restrict__ lc,
                               unsigned int* __restrict__ c8,
                               unsigned int* __restrict__ cT8){
    int t = blockIdx.x*256 + threadIdx.x;
    float4 v = ((const float4*)lc)[t];
    float s0 = (v.x>20.f)?v.x:log1pf(expf(v.x));
    float s1 = (v.y>20.f)?v.y:log1pf(expf(v.y));
    float s2 = (v.z>20.f)?v.z:log1pf(expf(v.z));
    float s3 = (v.w>20.f)?v.w:log1pf(expf(v.w));
    unsigned int d = f32_to_e4m3(s0*4096.f) | (f32_to_e4m3(s1*4096.f)<<8)
                   | (f32_to_e4m3(s2*4096.f)<<16) | (f32_to_e4m3(s3*4096.f)<<24);
    c8[t] = d;
    int f  = t<<2;
    int md = f>>8, c = (f>>4)&15, r = f&15;
    const float* s = lc + (md<<8) + c;
    float x0 = s[(r+0)<<4], x1 = s[(r+1)<<4], x2 = s[(r+2)<<4], x3 = s[(r+3)<<4];
    x0 = (x0>20.f)?x0:log1pf(expf(x0));
    x1 = (x1>20.f)?x1:log1pf(expf(x1));
    x2 = (x2>20.f)?x2:log1pf(expf(x2));
    x3 = (x3>20.f)?x3:log1pf(expf(x3));
    unsigned int dT = f32_to_e4m3(x0*4096.f) | (f32_to_e4m3(x1*4096.f)<<8)
                    | (f32_to_e4m3(x2*4096.f)<<16) | (f32_to_e4m3(x3*4096.f)<<24);
    cT8[t] = dT;
}

__global__ void k_bars_fp8(const unsigned char* __restrict__ c8, float* __restrict__ bars4){
    int b = blockIdx.x, t = threadIdx.x;
    int m = b>>2, dq = b&3;
    const unsigned char* p = c8 + m*65536 + dq*64*256 + t;
    float s = 0.f;
    #pragma unroll 16
    for (int d=0; d<64; d++) s += e4m3_to_f32(p[d*256]);
    bars4[dq*4096 + m*256 + t] = s;
}

__global__ void k_norm2(const float* __restrict__ bars4, float* __restrict__ lognorm){
    __shared__ float sbars[16*256];
    __shared__ float cur[256];
    int t = threadIdx.x, i = t>>4, j = t&15;
    for (int m=0;m<16;m++){
        int o = m*256 + t;
        sbars[o] = bars4[o] + bars4[4096+o] + bars4[8192+o] + bars4[12288+o];
    }
    cur[t] = (i==j)?1.f:0.f;
    __syncthreads();
    for (int m=0;m<16;m++){
        float s = 0.f;
        #pragma unroll
        for (int k=0;k<16;k++) s += cur[i*16+k]*sbars[m*256 + k*16 + j];
        s *= 0.000244140625f; // 2^-12 cancels the 4096x core scale
        __syncthreads();
        cur[t] = s;
        __syncthreads();
    }
    if (t==0){
        float tr=0.f;
        #pragma unroll
        for (int k=0;k<16;k++) tr += cur[k*17];
        lognorm[0] = logf(tr) + 192.0f*0.69314718055994531f; // + log(4096^16)
    }
}

// Split-wave pair gather: lanes 0-31 load sample a's mode-k fragment, lanes
// 32-63 sample b's (same laneoffB pattern as validated r12; per-half index).
// 16 loads fetch BOTH samples' 16 leaf matrices.
static __device__ __forceinline__ void gatherP(v2u* F,
        const int* __restrict__ ipa, const int* __restrict__ ipb,
        const unsigned char* __restrict__ c8, const unsigned char* __restrict__ cT8,
        int laneoffB, bool lo){
    #pragma unroll
    for (int k=0;k<16;k++){
        int ix = lo ? ipa[k] : ipb[k];                 // per-half (cndmask of 2 s_loads)
        const unsigned char* tp = (k&1)? cT8 : c8;
        F[k] = *(const v2u*)(tp + (((k<<8)|ix)<<8) + laneoffB);
    }
}

// Level 1 for a PAIR via K=32 fp8 MFMA. Sample a's matrix occupies k0-15
// (lanes 0-31), sample b's occupies k16-31 (lanes 32-63) NATURALLY from the
// split load. Complementary A-masking selects the live K-half; B is the raw
// loaded register for both samples (dead half multiplied by zeroed A).
// Orientation logic (i&1 role swap) verbatim from validated r7-r12.
static __device__ __forceinline__ void tree_level1_pair(const v2u* F, bool lo,
        unsigned int* c1loA, unsigned int* c1hiA,
        unsigned int* c1loB, unsigned int* c1hiB){
    #pragma unroll
    for (int i=0;i<8;i++){
        v2u fe = F[2*i];
        v2u fo = F[2*i+1];
        v2u fx = (i&1)? fe : fo;       // A-role source
        v2u bz = (i&1)? fo : fe;       // B-role source (shared by both samples)
        v2u aa, ab;
        aa.x = lo ? fx.x : 0u;  aa.y = lo ? fx.y : 0u;   // sample a: k0-15 live
        ab.x = lo ? 0u : fx.x;  ab.y = lo ? 0u : fx.y;   // sample b: k16-31 live
        FL A0; A0.u = aa;
        FL A1; A1.u = ab;
        FL B;  B.u  = bz;
        v4f z = {0.f,0.f,0.f,0.f};
        v4f accA = __builtin_amdgcn_mfma_f32_16x16x32_fp8_fp8(A0.l, B.l, z, 0,0,0);
        v4f accB = __builtin_amdgcn_mfma_f32_16x16x32_fp8_fp8(A1.l, B.l, z, 0,0,0);
        CVT_ACC_TO_B(c1loA[i], c1hiA[i], accA);
        CVT_ACC_TO_B(c1loB[i], c1hiB[i], accB);
    }
}

// Levels 2-3, bf16 (validated rounds 4-12 verbatim).
static __device__ __forceinline__ float tree_level23(const unsigned int* c1lo,
        const unsigned int* c1hi){
    unsigned int c2lo[4], c2hi[4];
    #pragma unroll
    for (int j=0;j<4;j++){
        FU A,B;
        if (j&1){ A.u=(v2u){c1lo[2*j],c1hi[2*j]};     B.u=(v2u){c1lo[2*j+1],c1hi[2*j+1]}; }
        else    { A.u=(v2u){c1lo[2*j+1],c1hi[2*j+1]}; B.u=(v2u){c1lo[2*j],c1hi[2*j]};     }
        v4f z={0.f,0.f,0.f,0.f};
        v4f acc=__builtin_amdgcn_mfma_f32_16x16x16bf16_1k(A.s,B.s,z,0,0,0);
        CVT_ACC_TO_B(c2lo[j],c2hi[j],acc);
    }
    FU A0,B0,A1,B1;
    A0.u=(v2u){c2lo[1],c2hi[1]}; B0.u=(v2u){c2lo[0],c2hi[0]};
    A1.u=(v2u){c2lo[2],c2hi[2]}; B1.u=(v2u){c2lo[3],c2hi[3]};
    v4f z={0.f,0.f,0.f,0.f};
    v4f aL=__builtin_amdgcn_mfma_f32_16x16x16bf16_1k(A0.s,B0.s,z,0,0,0);
    v4f aR=__builtin_amdgcn_mfma_f32_16x16x16bf16_1k(A1.s,B1.s,z,0,0,0);
    return aL[0]*aR[0]+aL[1]*aR[1]+aL[2]*aR[2]+aL[3]*aR[3];
}

__global__ __launch_bounds__(256) void k_chain12(const int* __restrict__ idx,
    const unsigned char* __restrict__ c8, const unsigned char* __restrict__ cT8,
    const float* __restrict__ lognorm, float* __restrict__ out)
{
    const int lane = threadIdx.x & 63;
    const int wq   = __builtin_amdgcn_readfirstlane(threadIdx.x >> 6);
    const int wave = (blockIdx.x<<2) + wq;
    const int row  = lane & 15;
    const int laneoffB = row*16 + ((lane>>4)&1)*8;   // bytes; validated r12 pattern
    const bool lo  = (lane < 32);                    // wave-half flag
    const float L = lognorm[0];
    const int s0 = wave * SPW;
    const int* __restrict__ ip = idx + (s0<<4);

    v2u FA[16], FB[16];
    unsigned int c1loA[8], c1hiA[8], c1loB[8], c1hiB[8];
    float d0,d1,d2,d3;

    // pair 0 (samples s0, s0+1) + pair 1 (s0+2, s0+3)
    gatherP(FA, ip,    ip+16, c8, cT8, laneoffB, lo);
    tree_level1_pair(FA, lo, c1loA, c1hiA, c1loB, c1hiB);
    gatherP(FB, ip+32, ip+48, c8, cT8, laneoffB, lo);
    d0 = tree_level23(c1loA, c1hiA);
    d1 = tree_level23(c1loB, c1hiB);

    tree_level1_pair(FB, lo, c1loA, c1hiA, c1loB, c1hiB);
    d2 = tree_level23(c1loA, c1hiA);
    d3 = tree_level23(c1loB, c1hiB);

    // batched butterfly: 4 independent chains (validated rounds 8-12)
    #pragma unroll
    for (int off=32; off>0; off>>=1){
        d0 += __shfl_xor(d0, off, 64);
        d1 += __shfl_xor(d1, off, 64);
        d2 += __shfl_xor(d2, off, 64);
        d3 += __shfl_xor(d3, off, 64);
    }
    float res = (lane==0)?d0:(lane==1)?d1:(lane==2)?d2:(lane==3)?d3:0.f;

    if (lane < SPW){
        float o;
        if (!(L > -1e30f && L < 1e30f)) o = -5555.0f;   // lognorm bad
        else if (res > 0.f)             o = logf(res) - L;
        else                            o = -6666.0f;   // non-positive trace
        out[s0 + lane] = o;
    }
}

extern "C" void kernel_launch(void* const* d_in, const int* in_sizes, int n_in,
                              void* d_out, int out_size, void* d_ws, size_t ws_size,
                              hipStream_t stream)
{
    const int*   idx = (const int*)d_in[0];
    const float* lc  = (const float*)d_in[1];
    float* out = (float*)d_out;

    const size_t C8_B    = (size_t)16*256*256;            // 1MB per fp8 table
    const size_t BARS4_B = (size_t)4*16*256*4;            // 64KB
    const size_t WS_NEED = 2*C8_B + BARS4_B + 4;
    if (ws_size < WS_NEED) return;   // signature: out stays 0 -> absmax ~= 89

    unsigned int* c8   = (unsigned int*)d_ws;
    unsigned int* cT8  = (unsigned int*)((char*)d_ws + C8_B);
    float* bars4   = (float*)((char*)d_ws + 2*C8_B);
    float* lognorm = (float*)((char*)d_ws + 2*C8_B + BARS4_B);

    k_softplus_fp8<<<1024, 256, 0, stream>>>(lc, c8, cT8);
    k_bars_fp8    <<<64,   256, 0, stream>>>((const unsigned char*)c8, bars4);
    k_norm2       <<<1,    256, 0, stream>>>(bars4, lognorm);
    int nblocks = out_size / (SPW*4);   // 4 waves/block -> 8192 blocks
    k_chain12     <<<nblocks, 256, 0, stream>>>(idx, (const unsigned char*)c8,
                                                (const unsigned char*)cT8, lognorm, out);
}